// Round 3
// baseline (150.032 us; speedup 1.0000x reference)
//
#include <hip/hip_runtime.h>
#include <hip/hip_bf16.h>
#include <math.h>

typedef __attribute__((ext_vector_type(8))) short short8;
typedef __attribute__((ext_vector_type(4))) float floatx4;

#define MARGIN_C    0.09f
#define ONE_M_EPS   0.99999f
#define NCLS        64
#define MEMSTRIDE   256

__device__ __forceinline__ unsigned short f2bf(float f) {
    unsigned u = __float_as_uint(f);
    u += 0x7fffu + ((u >> 16) & 1u);
    return (unsigned short)(u >> 16);
}
// order-preserving float->uint key (for atomicMax on floats incl. negatives)
__device__ __forceinline__ unsigned fkey(float f) {
    unsigned u = __float_as_uint(f);
    return (u >> 31) ? ~u : (u | 0x80000000u);
}
__device__ __forceinline__ float fdec(unsigned k) {
    return __uint_as_float((k >> 31) ? (k & 0x7fffffffu) : ~k);
}

// ---------- fp32 -> bf16 cvt; also zero the 4 stat arrays (4*Bn floats) ------
__global__ __launch_bounds__(256) void cvt_bf16(const float* __restrict__ in,
                                                unsigned short* __restrict__ out,
                                                float* __restrict__ statz,
                                                int n4, int nz4) {
    int i = blockIdx.x * 256 + threadIdx.x;
    if (i < nz4) ((float4*)statz)[i] = make_float4(0.f, 0.f, 0.f, 0.f);
    if (i >= n4) return;
    float4 v = ((const float4*)in)[i];
    ushort4 o;
    o.x = f2bf(v.x); o.y = f2bf(v.y); o.z = f2bf(v.z); o.w = f2bf(v.w);
    ((ushort4*)out)[i] = o;
}

// ---------- per-class member lists ------------------------------------------
__global__ __launch_bounds__(256) void build_members(const int* __restrict__ labels,
                                                     int* __restrict__ members,
                                                     int* __restrict__ classCount, int Bn) {
    __shared__ int cnt;
    const int c = blockIdx.x;
    if (threadIdx.x == 0) cnt = 0;
    __syncthreads();
    for (int j = threadIdx.x; j < Bn; j += 256) {
        if (labels[j] == c) {
            int p = atomicAdd(&cnt, 1);
            if (p < MEMSTRIDE) members[c * MEMSTRIDE + p] = j;
        }
    }
    __syncthreads();
    if (threadIdx.x == 0) classCount[c] = (cnt < MEMSTRIDE) ? cnt : MEMSTRIDE;
}

// ---------- GEMM (symmetric, lower-tri tiles) + fused negative stats --------
// 128x128 tile, BK=32, reg-prefetch double-buffered LDS. No sim materialized:
// epilogue reduces exp(40*s)/max(s) over negatives per row -> atomics.
__global__ __launch_bounds__(256) void gemm_fused(const unsigned short* __restrict__ fb,
                                                  const int* __restrict__ labels,
                                                  float* __restrict__ negsum,
                                                  unsigned* __restrict__ negmax,
                                                  int Bn, int Dn) {
    __shared__ __align__(16) unsigned short As[2][4096];
    __shared__ __align__(16) unsigned short Bs[2][4096];
    __shared__ int Lrow[128], Lcol[128];

    const int bid = blockIdx.x;
    int by = (int)((sqrtf(8.f * (float)bid + 1.f) - 1.f) * 0.5f);
    while ((by + 1) * (by + 2) / 2 <= bid) by++;
    while (by * (by + 1) / 2 > bid) by--;
    const int bx = bid - by * (by + 1) / 2;

    const int t = threadIdx.x;
    const int wave = t >> 6, lane = t & 63;
    const int wr = wave >> 1, wc = wave & 1;
    const int quad = lane >> 4, m16 = lane & 15;

    if (t < 128) Lrow[t] = labels[by * 128 + t];
    else         Lcol[t - 128] = labels[bx * 128 + (t - 128)];

    // staging: thread t covers LDS rows lr and lr+64, 16B granule slot (k-rotated)
    const int lr = t >> 2, slot = t & 3, kf = (slot + lr) & 3;
    const unsigned short* gA0 = fb + (size_t)(by * 128 + lr) * Dn + kf * 8;
    const unsigned short* gB0 = fb + (size_t)(bx * 128 + lr) * Dn + kf * 8;
    const unsigned short* gA1 = gA0 + (size_t)64 * Dn;
    const unsigned short* gB1 = gB0 + (size_t)64 * Dn;

    floatx4 acc[4][4];
#pragma unroll
    for (int i = 0; i < 4; i++)
#pragma unroll
        for (int j = 0; j < 4; j++) acc[i][j] = (floatx4){0.f, 0.f, 0.f, 0.f};

    const int fragA = (wr * 64 + m16) * 32 + ((quad - m16) & 3) * 8;
    const int fragB = (wc * 64 + m16) * 32 + ((quad - m16) & 3) * 8;

    const int NS = Dn / 32;
    uint4 ra0 = *(const uint4*)gA0, ra1 = *(const uint4*)gA1;
    uint4 rb0 = *(const uint4*)gB0, rb1 = *(const uint4*)gB1;
    *(uint4*)(&As[0][t * 8]) = ra0;  *(uint4*)(&As[0][2048 + t * 8]) = ra1;
    *(uint4*)(&Bs[0][t * 8]) = rb0;  *(uint4*)(&Bs[0][2048 + t * 8]) = rb1;
    ra0 = *(const uint4*)(gA0 + 32); ra1 = *(const uint4*)(gA1 + 32);
    rb0 = *(const uint4*)(gB0 + 32); rb1 = *(const uint4*)(gB1 + 32);
    __syncthreads();

    for (int s = 0; s < NS; s++) {
        const unsigned short* as_ = As[s & 1];
        const unsigned short* bs_ = Bs[s & 1];
        short8 af[4], bfr[4];
#pragma unroll
        for (int i = 0; i < 4; i++) af[i]  = *(const short8*)(as_ + fragA + i * 512);
#pragma unroll
        for (int i = 0; i < 4; i++) bfr[i] = *(const short8*)(bs_ + fragB + i * 512);
#pragma unroll
        for (int i = 0; i < 4; i++)
#pragma unroll
            for (int j = 0; j < 4; j++)
                acc[i][j] = __builtin_amdgcn_mfma_f32_16x16x32_bf16(af[i], bfr[j], acc[i][j], 0, 0, 0);
        if (s + 1 < NS) {
            __syncthreads();
            unsigned short* aw = As[(s + 1) & 1];
            unsigned short* bw = Bs[(s + 1) & 1];
            *(uint4*)(&aw[t * 8]) = ra0;  *(uint4*)(&aw[2048 + t * 8]) = ra1;
            *(uint4*)(&bw[t * 8]) = rb0;  *(uint4*)(&bw[2048 + t * 8]) = rb1;
            if (s + 2 < NS) {
                const int ko = (s + 2) * 32;
                ra0 = *(const uint4*)(gA0 + ko); ra1 = *(const uint4*)(gA1 + ko);
                rb0 = *(const uint4*)(gB0 + ko); rb1 = *(const uint4*)(gB1 + ko);
            }
            __syncthreads();
        }
    }

    // ----- fused negative-stat epilogue -----
    // C/D layout: col = m16 (+j*16), row = quad*4 + r (+i*16)
    int cl[4];
#pragma unroll
    for (int j = 0; j < 4; j++) cl[j] = Lcol[wc * 64 + j * 16 + m16];

    float nsm[4] = {0.f, 0.f, 0.f, 0.f};
    float nmm[4] = {-INFINITY, -INFINITY, -INFINITY, -INFINITY};

#pragma unroll
    for (int i = 0; i < 4; i++) {
#pragma unroll
        for (int r = 0; r < 4; r++) {
            const int rowl = wr * 64 + i * 16 + quad * 4 + r;
            const int rl = Lrow[rowl];
            float ns = 0.f, nm = -INFINITY;
#pragma unroll
            for (int j = 0; j < 4; j++) {
                float s = acc[i][j][r];
                if (cl[j] != rl) {
                    float e = __expf(40.f * s);
                    ns += e;
                    nm = fmaxf(nm, s);
                    nsm[j] += e;
                    nmm[j] = fmaxf(nmm[j], s);
                }
            }
            // reduce over the 16 lanes of this quad (m16 = 0..15)
#pragma unroll
            for (int o = 8; o; o >>= 1) {
                ns += __shfl_down(ns, o, 64);
                nm = fmaxf(nm, __shfl_down(nm, o, 64));
            }
            if (m16 == 0) {
                const int gr = by * 128 + rowl;
                atomicAdd(negsum + gr, ns);
                atomicMax(negmax + gr, fkey(nm));
            }
        }
    }
    if (bx != by) {  // mirror contribution: this tile's cols are rows bx*128..
#pragma unroll
        for (int j = 0; j < 4; j++) {
            float v = nsm[j], m = nmm[j];
            v += __shfl_down(v, 16, 64);
            m = fmaxf(m, __shfl_down(m, 16, 64));
            v += __shfl_down(v, 32, 64);
            m = fmaxf(m, __shfl_down(m, 32, 64));
            if (quad == 0) {
                const int gc = bx * 128 + wc * 64 + j * 16 + m16;
                atomicAdd(negsum + gc, v);
                atomicMax(negmax + gc, fkey(m));
            }
        }
    }
}

// ---------- per-class gram (gathered rows) -> positive stats ----------------
__global__ __launch_bounds__(256) void pos_class(const unsigned short* __restrict__ fb,
                                                 const int* __restrict__ members,
                                                 const int* __restrict__ classCount,
                                                 const unsigned* __restrict__ negmax,
                                                 float* __restrict__ possum,
                                                 float* __restrict__ nposf,
                                                 int Bn, int Dn) {
    __shared__ __align__(16) unsigned short As[2][4096];
    __shared__ __align__(16) unsigned short Bs[2][4096];

    const int c = blockIdx.x;
    const int n = classCount[c];
    if (n <= 0) return;
    const int base = c * MEMSTRIDE;
    const int m0 = members[base];

    const int t = threadIdx.x;
    const int wave = t >> 6, lane = t & 63;
    const int wr = wave >> 1, wc = wave & 1;
    const int quad = lane >> 4, m16 = lane & 15;

    const int lr = t >> 2, slot = t & 3, kf = (slot + lr) & 3;
    const int fragA = (wr * 64 + m16) * 32 + ((quad - m16) & 3) * 8;
    const int fragB = (wc * 64 + m16) * 32 + ((quad - m16) & 3) * 8;
    const int NS = Dn / 32;

    for (int r0 = 0; r0 < n; r0 += 128) {
        for (int c0 = 0; c0 < n; c0 += 128) {
            __syncthreads();  // protect LDS across tile iterations
            const int i0 = r0 + lr, i1 = r0 + lr + 64;
            const int j0 = c0 + lr, j1 = c0 + lr + 64;
            const int a0i = (i0 < n) ? members[base + i0] : m0;
            const int a1i = (i1 < n) ? members[base + i1] : m0;
            const int b0i = (j0 < n) ? members[base + j0] : m0;
            const int b1i = (j1 < n) ? members[base + j1] : m0;
            const unsigned short* gA0 = fb + (size_t)a0i * Dn + kf * 8;
            const unsigned short* gA1 = fb + (size_t)a1i * Dn + kf * 8;
            const unsigned short* gB0 = fb + (size_t)b0i * Dn + kf * 8;
            const unsigned short* gB1 = fb + (size_t)b1i * Dn + kf * 8;

            floatx4 acc[4][4];
#pragma unroll
            for (int i = 0; i < 4; i++)
#pragma unroll
                for (int j = 0; j < 4; j++) acc[i][j] = (floatx4){0.f, 0.f, 0.f, 0.f};

            uint4 ra0 = *(const uint4*)gA0, ra1 = *(const uint4*)gA1;
            uint4 rb0 = *(const uint4*)gB0, rb1 = *(const uint4*)gB1;
            *(uint4*)(&As[0][t * 8]) = ra0;  *(uint4*)(&As[0][2048 + t * 8]) = ra1;
            *(uint4*)(&Bs[0][t * 8]) = rb0;  *(uint4*)(&Bs[0][2048 + t * 8]) = rb1;
            ra0 = *(const uint4*)(gA0 + 32); ra1 = *(const uint4*)(gA1 + 32);
            rb0 = *(const uint4*)(gB0 + 32); rb1 = *(const uint4*)(gB1 + 32);
            __syncthreads();

            for (int s = 0; s < NS; s++) {
                const unsigned short* as_ = As[s & 1];
                const unsigned short* bs_ = Bs[s & 1];
                short8 af[4], bfr[4];
#pragma unroll
                for (int i = 0; i < 4; i++) af[i]  = *(const short8*)(as_ + fragA + i * 512);
#pragma unroll
                for (int i = 0; i < 4; i++) bfr[i] = *(const short8*)(bs_ + fragB + i * 512);
#pragma unroll
                for (int i = 0; i < 4; i++)
#pragma unroll
                    for (int j = 0; j < 4; j++)
                        acc[i][j] = __builtin_amdgcn_mfma_f32_16x16x32_bf16(af[i], bfr[j], acc[i][j], 0, 0, 0);
                if (s + 1 < NS) {
                    __syncthreads();
                    unsigned short* aw = As[(s + 1) & 1];
                    unsigned short* bw = Bs[(s + 1) & 1];
                    *(uint4*)(&aw[t * 8]) = ra0;  *(uint4*)(&aw[2048 + t * 8]) = ra1;
                    *(uint4*)(&bw[t * 8]) = rb0;  *(uint4*)(&bw[2048 + t * 8]) = rb1;
                    if (s + 2 < NS) {
                        const int ko = (s + 2) * 32;
                        ra0 = *(const uint4*)(gA0 + ko); ra1 = *(const uint4*)(gA1 + ko);
                        rb0 = *(const uint4*)(gB0 + ko); rb1 = *(const uint4*)(gB1 + ko);
                    }
                    __syncthreads();
                }
            }

            // positive-stat epilogue (all pairs same class; self killed by margin)
#pragma unroll
            for (int i = 0; i < 4; i++) {
#pragma unroll
                for (int r = 0; r < 4; r++) {
                    const int rowl = wr * 64 + i * 16 + quad * 4 + r;
                    const int idx = r0 + rowl;
                    const bool vr = idx < n;
                    const int gi = vr ? members[base + idx] : 0;
                    const float mx = vr ? fdec(negmax[gi]) : -1e30f;
                    float pp = 0.f, pc = 0.f;
#pragma unroll
                    for (int j = 0; j < 4; j++) {
                        const int cj = c0 + wc * 64 + j * 16 + m16;
                        float s = acc[i][j][r];
                        if (vr && cj < n && s < ONE_M_EPS && (s - MARGIN_C) < mx) {
                            pp += __expf(-2.f * s);
                            pc += 1.f;
                        }
                    }
#pragma unroll
                    for (int o = 8; o; o >>= 1) {
                        pp += __shfl_down(pp, o, 64);
                        pc += __shfl_down(pc, o, 64);
                    }
                    if (m16 == 0 && vr) {
                        atomicAdd(possum + gi, pp);
                        atomicAdd(nposf + gi, pc);
                    }
                }
            }
        }
    }
}

// ---------- finalize: per-row loss + global mean (single block) -------------
__global__ __launch_bounds__(1024) void finalize(const float* __restrict__ negsum,
                                                 const float* __restrict__ possum,
                                                 const float* __restrict__ nposf,
                                                 const int* __restrict__ labels,
                                                 const int* __restrict__ classCount,
                                                 float* __restrict__ out, int Bn) {
    __shared__ float red[16];
    const int t = threadIdx.x;
    const int wave = t >> 6, lane = t & 63;
    float acc = 0.f;
    for (int i = t; i < Bn; i += 1024) {
        const int lab = labels[i];
        const int nneg = Bn - classCount[lab];
        const float np = nposf[i];
        if (nneg >= 1 && np >= 0.5f) {
            float pl = 0.5f * logf((possum[i] + expf(-2.f * 0.501f)) / (np + 1.f));
            float nl = (1.f / 40.f) * logf((negsum[i] + expf(40.f * 0.531f)) / ((float)nneg + 1.f));
            acc += logf(5.33f + expf(pl + nl));
        }
    }
#pragma unroll
    for (int o = 32; o; o >>= 1) acc += __shfl_down(acc, o, 64);
    if (lane == 0) red[wave] = acc;
    __syncthreads();
    if (t == 0) {
        float s = 0.f;
        for (int w = 0; w < 16; w++) s += red[w];
        out[0] = s / (float)Bn;
    }
}

extern "C" void kernel_launch(void* const* d_in, const int* in_sizes, int n_in,
                              void* d_out, int out_size, void* d_ws, size_t ws_size,
                              hipStream_t stream) {
    const float* feats = (const float*)d_in[0];
    const int* labels  = (const int*)d_in[1];
    float* out = (float*)d_out;

    const int Bn = in_sizes[1];           // 4096
    const int Dn = in_sizes[0] / Bn;      // 1024

    unsigned short* fb = (unsigned short*)d_ws;                 // bf16 feats [Bn][Dn]
    float* stats   = (float*)(fb + (size_t)Bn * Dn);
    float* negsum  = stats;                                     // [Bn]
    unsigned* negmax = (unsigned*)(stats + Bn);                 // [Bn] (keyed)
    float* possum  = stats + 2 * Bn;                            // [Bn]
    float* nposf   = stats + 3 * Bn;                            // [Bn]
    int* classCount = (int*)(stats + 4 * Bn);                   // [NCLS]
    int* members    = classCount + NCLS;                        // [NCLS][MEMSTRIDE]

    const int n4 = (Bn * Dn) / 4;
    cvt_bf16<<<(n4 + 255) / 256, 256, 0, stream>>>(feats, fb, stats, n4, Bn);

    build_members<<<NCLS, 256, 0, stream>>>(labels, members, classCount, Bn);

    const int nt = Bn / 128;
    const int ntri = nt * (nt + 1) / 2;   // 528
    gemm_fused<<<ntri, 256, 0, stream>>>(fb, labels, negsum, negmax, Bn, Dn);

    pos_class<<<NCLS, 256, 0, stream>>>(fb, members, classCount, negmax, possum, nposf, Bn, Dn);

    finalize<<<1, 1024, 0, stream>>>(negsum, possum, nposf, labels, classCount, out, Bn);
}